// Round 3
// baseline (304.526 us; speedup 1.0000x reference)
//
#include <hip/hip_runtime.h>
#include <hip/hip_bf16.h>
#include <stdint.h>

// ExpanderLinear: y[t,o] = sum_i x[t,i] * (w[o,i]*mask[o,i]) + bias[o]
// M=8192, K=4096, N=4096. f32 in/out, bf16 MFMA compute.
// GEMM: 256x256 tile, 8 waves, ring-5 LDS units (160 KiB), m201-faithful
// quadrant phases, counted vmcnt(8) (depth 8-12, never 0 in loop),
// T1 XCD swizzle + T2 LDS swizzle + T5 setprio.

typedef __attribute__((ext_vector_type(4))) float          f32x4;
typedef __attribute__((ext_vector_type(4))) int            i32x4;
typedef __attribute__((ext_vector_type(4))) unsigned short u16x4;
typedef __attribute__((ext_vector_type(8))) __bf16         bf16x8;

static constexpr int M = 8192;
static constexpr int N = 4096;
static constexpr int K = 4096;

#define BM 256
#define BN 256
#define NT (K / 64)

#define GLOBAL_AS(p) ((const __attribute__((address_space(1))) void*)(p))
#define LDS_AS(p)    ((__attribute__((address_space(3))) void*)(p))

__device__ __forceinline__ unsigned short f2bf(float f) {
    unsigned int u = __float_as_uint(f);
    u = (u + 0x7fffu + ((u >> 16) & 1u)) >> 16;
    return (unsigned short)u;
}

// ---- prep 1: x f32 -> bf16 ----
__global__ void cvt_x_kernel(const float* __restrict__ x,
                             unsigned short* __restrict__ out) {
    int i = blockIdx.x * blockDim.x + threadIdx.x;
    f32x4 v = ((const f32x4*)x)[i];
    u16x4 r;
    r.x = f2bf(v.x); r.y = f2bf(v.y); r.z = f2bf(v.z); r.w = f2bf(v.w);
    ((u16x4*)out)[i] = r;
}

// ---- prep 2: (w * mask) f32 -> bf16, fused ----
__global__ void cvt_wm_kernel(const float* __restrict__ w,
                              const int* __restrict__ mask,
                              unsigned short* __restrict__ out) {
    int i = blockIdx.x * blockDim.x + threadIdx.x;
    f32x4 v = ((const f32x4*)w)[i];
    i32x4 m = ((const i32x4*)mask)[i];
    u16x4 r;
    r.x = m.x ? f2bf(v.x) : (unsigned short)0;
    r.y = m.y ? f2bf(v.y) : (unsigned short)0;
    r.z = m.z ? f2bf(v.z) : (unsigned short)0;
    r.w = m.w ? f2bf(v.w) : (unsigned short)0;
    ((u16x4*)out)[i] = r;
}

// ---- main GEMM ----
// LDS: A-ring = 5 units of [256 rows][32 bf16] (16KB each), B-ring same.
// Unit for (tile t, k-half h) lives in slot (2t+h) % 5.
// During iter t: read slots {2t,2t+1}%5; stage t+1 kh1 -> (2t+3)%5 and
// t+2 kh0 -> (2t+4)%5; slot (2t+2)%5 holds t+1 kh0 (staged at t-1).
// Swizzle (within 128B row-pair): phys3 = (((row&1)<<2)|fq) ^ ((row>>1)&7).
// LDS writes stay linear (global_load_lds); the global SOURCE is pre-swizzled.
__global__ void __launch_bounds__(512, 2)
gemm8_bf16(const unsigned short* __restrict__ A,   // [M][K] bf16 bits
           const unsigned short* __restrict__ B,   // [N][K] bf16 bits
           const float* __restrict__ bias,         // [N]
           float* __restrict__ C) {                // [M][N] f32
    extern __shared__ unsigned short lds[];
    unsigned short* __restrict__ Au = lds;            // 5 * 8192 elems
    unsigned short* __restrict__ Bu = lds + 40960;    // 5 * 8192 elems

    const int tid  = threadIdx.x;
    const int lane = tid & 63;
    const int wave = tid >> 6;

    // T1: XCD-aware bijective swizzle (nwg = 512, % 8 == 0)
    const int bid = blockIdx.x;
    const int swz = (bid & 7) * 64 + (bid >> 3);
    const int brow = (swz >> 4) * BM;          // ntn = 16
    const int bcol = (swz & 15) * BN;

    const int wrow = (wave >> 2) * 128;        // wave output rows
    const int wcol = (wave & 3) * 64;          // wave output cols
    const int fr = lane & 15;                  // fragment row/col
    const int fq = lane >> 4;                  // k-subgroup

    // read-side swizzle bases (byte offsets within a unit)
    const int s3r   = (((fr & 1) << 2) | fq) ^ (fr >> 1);
    const int abase = wrow * 64 + (fr >> 1) * 128 + s3r * 16;   // + m*1024
    const int bbase = wcol * 64 + (fr >> 1) * 128 + s3r * 16;   // + n*1024

    // write-side: lane's linear LDS slot -> logical (row, col) in global
    const int l8 = lane & 7, lh = lane >> 3;
    const int s3w    = l8 ^ lh;
    const int wrow_l = 2 * lh + (s3w >> 2);    // row within 16-row call block
    const int wcol_l = (s3w & 3) * 8;          // bf16 col within 32-col unit

    const unsigned short* __restrict__ Ag = A + (size_t)brow * K;
    const unsigned short* __restrict__ Bg = B + (size_t)bcol * K;

    f32x4 acc[8][4];
#pragma unroll
    for (int m = 0; m < 8; ++m)
#pragma unroll
        for (int n = 0; n < 4; ++n) acc[m][n] = (f32x4)(0.0f);

    bf16x8 af[4], bfv[4];

#define STG1(dst, src) __builtin_amdgcn_global_load_lds(GLOBAL_AS(src), LDS_AS(dst), 16, 0, 0)
#define STGA(slot, kcol) do {                                                   \
    STG1(Au + (slot) * 8192 + wave * 512,                                       \
         Ag + (size_t)(wave * 16 + wrow_l) * K + (kcol) + wcol_l);              \
    STG1(Au + (slot) * 8192 + (wave + 8) * 512,                                 \
         Ag + (size_t)((wave + 8) * 16 + wrow_l) * K + (kcol) + wcol_l);        \
  } while (0)
#define STGB(slot, kcol) do {                                                   \
    STG1(Bu + (slot) * 8192 + wave * 512,                                       \
         Bg + (size_t)(wave * 16 + wrow_l) * K + (kcol) + wcol_l);              \
    STG1(Bu + (slot) * 8192 + (wave + 8) * 512,                                 \
         Bg + (size_t)((wave + 8) * 16 + wrow_l) * K + (kcol) + wcol_l);        \
  } while (0)
#define LDA4(unit, m0) do {                                                     \
    const char* ub_ = (const char*)(Au + (unit) * 8192);                        \
    _Pragma("unroll")                                                           \
    for (int i = 0; i < 4; ++i)                                                 \
        af[i] = *(const bf16x8*)(ub_ + abase + ((m0) + i) * 1024);              \
  } while (0)
#define LDB4(unit) do {                                                         \
    const char* vb_ = (const char*)(Bu + (unit) * 8192);                        \
    _Pragma("unroll")                                                           \
    for (int n = 0; n < 4; ++n)                                                 \
        bfv[n] = *(const bf16x8*)(vb_ + bbase + n * 1024);                      \
  } while (0)
#define MM4(r0) do {                                                            \
    __builtin_amdgcn_s_setprio(1);                                              \
    _Pragma("unroll")                                                           \
    for (int i = 0; i < 4; ++i)                                                 \
      _Pragma("unroll")                                                         \
      for (int n = 0; n < 4; ++n)                                               \
        acc[(r0) + i][n] = __builtin_amdgcn_mfma_f32_16x16x32_bf16(             \
            af[i], bfv[n], acc[(r0) + i][n], 0, 0, 0);                          \
    __builtin_amdgcn_s_setprio(0);                                              \
  } while (0)
#define BAR   __builtin_amdgcn_s_barrier()
#define WLGKM asm volatile("s_waitcnt lgkmcnt(0)" ::: "memory")
#define WVM8  asm volatile("s_waitcnt vmcnt(8)" ::: "memory")
#define WVM0  asm volatile("s_waitcnt vmcnt(0)" ::: "memory")

    // prologue: stage t0 kh0 -> slot0, t0 kh1 -> slot1, t1 kh0 -> slot2
    STGA(0, 0);  STGB(0, 0);
    STGA(1, 32); STGB(1, 32);
    STGA(2, 64); STGB(2, 64);
    WVM8;   // drains slot0 (12 outstanding -> 8)
    BAR;

    int u0 = 0, u1 = 1, sP = 3, sQ = 4;   // sP: t+1 kh1, sQ: t+2 kh0
    for (int t = 0; t < NT; ++t) {
        const int kn1 = (t + 1 < NT) ? (t + 1) * 64 + 32 : 0;  // wrap: benign
        const int kn2 = (t + 2 < NT) ? (t + 2) * 64 : 0;       // wrap: benign
        // Phase A: u0, rows 0-3 (+ B frags for this k-half)
        LDA4(u0, 0); LDB4(u0); STGA(sP, kn1);
        BAR; WLGKM; MM4(0); BAR;
        // Phase B: u0, rows 4-7 (bfv reused)
        LDA4(u0, 4); STGB(sP, kn1);
        BAR; WLGKM; MM4(4); WVM8; BAR;   // drains sP(t-1) = u1(t) data
        // Phase C: u1, rows 0-3
        LDA4(u1, 0); LDB4(u1); STGA(sQ, kn2);
        BAR; WLGKM; MM4(0); BAR;
        // Phase D: u1, rows 4-7
        LDA4(u1, 4); STGB(sQ, kn2);
        BAR; WLGKM; MM4(4); WVM8; BAR;   // drains sQ(t-1) = u0(t+1) data
        // ring advance (+2 mod 5), uniform scalars
        u0 += 2; if (u0 >= 5) u0 -= 5;
        u1 += 2; if (u1 >= 5) u1 -= 5;
        sP += 2; if (sP >= 5) sP -= 5;
        sQ += 2; if (sQ >= 5) sQ -= 5;
    }
    WVM0;   // drain wrapped tail stages before exit

    // epilogue: C/D layout col=lane&15, row=(lane>>4)*4+reg [m89/m91]
    float bv[4];
#pragma unroll
    for (int n = 0; n < 4; ++n) bv[n] = bias[bcol + wcol + n * 16 + fr];
#pragma unroll
    for (int m = 0; m < 8; ++m) {
#pragma unroll
        for (int j = 0; j < 4; ++j) {
            const int row = brow + wrow + m * 16 + fq * 4 + j;
            float* crow = C + (size_t)row * N + bcol + wcol + fr;
#pragma unroll
            for (int n = 0; n < 4; ++n) crow[n * 16] = acc[m][n][j] + bv[n];
        }
    }
#undef STG1
#undef STGA
#undef STGB
#undef LDA4
#undef LDB4
#undef MM4
#undef BAR
#undef WLGKM
#undef WVM8
#undef WVM0
}

// ---- fallback (only if ws too small): f32 vector GEMM ----
__global__ void fallback_gemm(const float* __restrict__ x,
                              const float* __restrict__ w,
                              const int* __restrict__ mask,
                              const float* __restrict__ bias,
                              float* __restrict__ C) {
    const int tid = threadIdx.x;
    const int tx = tid & 15, ty = tid >> 4;
    const int brow = blockIdx.y * 64, bcol = blockIdx.x * 64;
    __shared__ float As[64][17];
    __shared__ float Ws[64][17];
    float acc[4][4] = {};
    for (int k0 = 0; k0 < K; k0 += 16) {
        __syncthreads();
        for (int i = tid; i < 64 * 16; i += 256) {
            int r = i >> 4, c = i & 15;
            As[r][c] = x[(size_t)(brow + r) * K + k0 + c];
            float wv = w[(size_t)(bcol + r) * K + k0 + c];
            Ws[r][c] = mask[(size_t)(bcol + r) * K + k0 + c] ? wv : 0.0f;
        }
        __syncthreads();
        for (int kk = 0; kk < 16; ++kk) {
            float a[4], b[4];
#pragma unroll
            for (int i = 0; i < 4; ++i) a[i] = As[ty * 4 + i][kk];
#pragma unroll
            for (int i = 0; i < 4; ++i) b[i] = Ws[tx * 4 + i][kk];
#pragma unroll
            for (int i = 0; i < 4; ++i)
#pragma unroll
                for (int j = 0; j < 4; ++j) acc[i][j] += a[i] * b[j];
        }
    }
    for (int i = 0; i < 4; ++i)
        for (int j = 0; j < 4; ++j) {
            int row = brow + ty * 4 + i, col = bcol + tx * 4 + j;
            C[(size_t)row * N + col] = acc[i][j] + bias[col];
        }
}

extern "C" void kernel_launch(void* const* d_in, const int* in_sizes, int n_in,
                              void* d_out, int out_size, void* d_ws, size_t ws_size,
                              hipStream_t stream) {
    const float* x    = (const float*)d_in[0];
    const float* w    = (const float*)d_in[1];
    const float* bias = (const float*)d_in[2];
    const int*   mask = (const int*)d_in[3];
    float* out = (float*)d_out;

    const size_t need = ((size_t)M * K + (size_t)N * K) * sizeof(unsigned short);
    if (ws_size >= need) {
        unsigned short* xb = (unsigned short*)d_ws;           // [M][K] bf16
        unsigned short* wb = xb + (size_t)M * K;              // [N][K] bf16
        (void)hipFuncSetAttribute((const void*)gemm8_bf16,
                                  hipFuncAttributeMaxDynamicSharedMemorySize,
                                  163840);
        cvt_x_kernel<<<(M * K / 4) / 256, 256, 0, stream>>>(x, xb);
        cvt_wm_kernel<<<(N * K / 4) / 256, 256, 0, stream>>>(w, mask, wb);
        gemm8_bf16<<<(M / BM) * (N / BN), 512, 163840, stream>>>(xb, wb, bias, out);
    } else {
        dim3 g(N / 64, M / 64);
        fallback_gemm<<<g, 256, 0, stream>>>(x, w, mask, bias, out);
    }
}